// Round 10
// baseline (750.999 us; speedup 1.0000x reference)
//
#include <hip/hip_runtime.h>
#include <math.h>

// ---------------- problem dims ----------------
#define NB 32
#define NT 64
#define NF 2048  // NB*NT frames

// ---------------- output float offsets ----------------
#define OUT_ZS    2097152
#define OUT_PRM   (OUT_ZS + 65536)
#define OUT_PRLS  (OUT_PRM + 65536)
#define OUT_PM    (OUT_PRLS + 65536)
#define OUT_PLS   (OUT_PM + 65536)
#define OUT_HF    (OUT_PLS + 65536)

// ---------------- workspace float offsets ----------------
#define WS_X1    0          // conv1 out bf16 / deconv2 out fp32
#define WS_X2    16777216   // conv2 out bf16 / deconv1 out bf16 (first half)
#define WS_X3    25165824   // conv3 out bf16; then posl1e+gia; then declin out bf16
#define WS_EMB   27262976   // 2048*64
#define WS_HS    27394048   // 64*32*128
#define WS_ENCT  27656192   // enc_pw^T (1024x64)
#define WS_DECT  27721728   // dec_pw^T (160x1024)
// bf16 recurrence weight packs
#define WS_WP1H  27885568   // 128x128 bf16
#define WS_WP2   27893760   // 128x128 bf16
#define WS_WP3   27901952   // 64x128 bf16
#define WS_WWHH  27906048   // 384x128 bf16
#define WS_WIHZ  27930624   // 384x32 bf16
// fp32 transposes for pri/pre
#define WS_QW1T  27936768   // 130x128
#define WS_QW2T  27953408   // 128x128
#define WS_QW3T  27969792   // 128x64
#define WS_PW1T  27977984   // 192x128
#define WS_WIHT  28002560   // 34x384
// conv/deconv MFMA weight packs (bf16 [tap][oc][ic]) in X2 second half
#define WS_WC2   (WS_X2 + 4194304)
#define WS_WC3   (WS_WC2 + 16384)
#define WS_WD1   (WS_WC3 + 32768)
#define WS_WD2   (WS_WD1 + 32768)
// step inputs (X3 region, after enclin)
#define WS_POSL1E WS_X3
#define WS_GIA    (WS_X3 + 262144)

// ==================== helpers ====================
typedef __attribute__((ext_vector_type(8))) short short8;
typedef __attribute__((ext_vector_type(4))) float floatx4;
union U4S8 { uint4 u; short8 s; };
union F4 { float4 v; float a[4]; };
__device__ __forceinline__ short8 u2s(uint4 u) { U4S8 x; x.u = u; return x.s; }
__device__ __forceinline__ float eluf(float a) { return (a > 0.f) ? a : expm1f(a); }
__device__ __forceinline__ float sigm(float a) { return 1.f / (1.f + expf(-a)); }
__device__ __forceinline__ unsigned short f2bf(float f) {
  unsigned int u = __float_as_uint(f);
  u += 0x7fffu + ((u >> 16) & 1u);
  return (unsigned short)(u >> 16);
}
__device__ __forceinline__ uint2 pk4(float a, float b, float c, float d) {
  uint2 r;
  r.x = (unsigned)f2bf(a) | ((unsigned)f2bf(b) << 16);
  r.y = (unsigned)f2bf(c) | ((unsigned)f2bf(d) << 16);
  return r;
}

// ==================== unified prep: fp32 transposes + bf16 packs ===========
// mode 10: fp32 transpose dst[c*A+r]=src[r*B+c] (A=rows,B=cols)
// mode 0: bf16 direct; 1: pos_w1 h-part; 2: wih z-part;
// mode 3: conv w [oc][ic][t]->[t][oc][ic]; 4: deconv w [ic][oc][t]->[t][oc][ic]
struct PP { const float* src; void* dst; int n; int mode; int A; int B; };
struct PPAll { PP m[16]; };

__global__ __launch_bounds__(256) void k_prep(PPAll a) {
  PP p = a.m[blockIdx.y];
  for (int i = blockIdx.x * 256 + threadIdx.x; i < p.n; i += gridDim.x * 256) {
    if (p.mode == 10) {
      const int r = i / p.B, c = i - r * p.B;
      ((float*)p.dst)[c * p.A + r] = p.src[i];
    } else {
      float v;
      if (p.mode == 0) v = p.src[i];
      else if (p.mode == 1) v = p.src[(i >> 7) * 192 + (i & 127)];
      else if (p.mode == 2) v = p.src[(i >> 5) * 34 + (i & 31)];
      else {
        const int ab = p.A * p.B;
        const int t = i / ab, rem = i - t * ab;
        const int oc = rem / p.B, ic = rem - oc * p.B;
        v = (p.mode == 3) ? p.src[(oc * p.B + ic) * 16 + t]
                          : p.src[(ic * p.A + oc) * 16 + t];
      }
      ((unsigned short*)p.dst)[i] = f2bf(v);
    }
  }
}

// ==================== conv1: 1x32x32 -> 32x16x16 (fp32 compute, bf16 out) ==
__global__ __launch_bounds__(256) void k_conv1(const float* __restrict__ obs,
    const float* __restrict__ w, const float* __restrict__ bias,
    unsigned short* __restrict__ out) {
  __shared__ float sIn[32 * 33];
  __shared__ float sW[512];
  __shared__ float sB[32];
  const int f = blockIdx.x, tid = threadIdx.x;
  const float* in = obs + f * 1024;
  for (int i = tid; i < 1024; i += 256) sIn[(i >> 5) * 33 + (i & 31)] = in[i];
  for (int i = tid; i < 512; i += 256) sW[i] = w[i];
  if (tid < 32) sB[tid] = bias[tid];
  __syncthreads();
  unsigned short* outf = out + (size_t)f * 8192;
  for (int r = tid; r < 512; r += 256) {       // r = oc*16 + oy
    const int oc = r >> 4, oy = r & 15;
    float acc[16];
    const float bv = sB[oc];
#pragma unroll
    for (int j = 0; j < 16; j++) acc[j] = bv;
#pragma unroll
    for (int ky = 0; ky < 4; ky++) {
      const int iy = 2 * oy + ky - 1;
      if (iy < 0 || iy >= 32) continue;
#pragma unroll
      for (int kx = 0; kx < 4; kx++) {
        const float wv = sW[oc * 16 + ky * 4 + kx];
#pragma unroll
        for (int j = 0; j < 16; j++) {
          const int ix = 2 * j + kx - 1;
          if (ix >= 0 && ix < 32) acc[j] += wv * sIn[iy * 33 + ix];
        }
      }
    }
#pragma unroll
    for (int j = 0; j < 16; j++)
      outf[(oy * 16 + j) * 32 + oc] = f2bf(fmaxf(acc[j], 0.f));
  }
}

// ==================== MFMA conv (k4 s2 p1, relu, bf16 in/out) ==============
template<int IC, int IH, int IW, int OC>
__global__ __launch_bounds__(256, 2) void k_conv_mfma(
    const unsigned short* __restrict__ xin,
    const unsigned short* __restrict__ wpk,
    const float* __restrict__ bias,
    unsigned short* __restrict__ yout) {
  constexpr int OH = IH / 2, OW = IW / 2, NPO = OH * OW, NTN = NPO / 16;
  constexpr int ICP = IC + 8, KS = IC / 32;
  constexpr int W2 = IW + 2, H2 = IH + 2, OCP = OC + 8;
  __shared__ __align__(16) unsigned short sIn[H2 * W2 * ICP];
  __shared__ __align__(16) unsigned short sOutT[NPO * OCP];
  const int f = blockIdx.x, tid = threadIdx.x;
  const int w = tid >> 6, l = tid & 63, q = l >> 4, n = l & 15;
  {
    unsigned int* z = (unsigned int*)sIn;
    for (int i = tid; i < H2 * W2 * ICP / 2; i += 256) z[i] = 0u;
  }
  __syncthreads();
  {
    const unsigned short* xf = xin + (size_t)f * IH * IW * IC;
    for (int i = tid; i < IH * IW * (IC / 8); i += 256) {
      const int px = i / (IC / 8), g = i - px * (IC / 8);
      const int iy = px / IW, ix = px - iy * IW;
      uint4 v = *reinterpret_cast<const uint4*>(xf + px * IC + g * 8);
      *reinterpret_cast<uint4*>(&sIn[((iy + 1) * W2 + (ix + 1)) * ICP + g * 8]) = v;
    }
  }
  __syncthreads();
  int base[NTN];
#pragma unroll
  for (int nt = 0; nt < NTN; nt++) {
    const int px = nt * 16 + n, oy = px / OW, ox = px - oy * OW;
    base[nt] = ((2 * oy + 1) * W2 + (2 * ox + 1)) * ICP + q * 8;
  }
  floatx4 acc[NTN];
#pragma unroll
  for (int nt = 0; nt < NTN; nt++) acc[nt] = (floatx4){0.f, 0.f, 0.f, 0.f};
  for (int ks = 0; ks < KS; ks++) {
    uint4 af[16];
#pragma unroll
    for (int t = 0; t < 16; t++)
      af[t] = *reinterpret_cast<const uint4*>(
          wpk + ((size_t)(t * OC + w * 16 + n) * IC + ks * 32 + q * 8));
#pragma unroll
    for (int t = 0; t < 16; t++) {
      const int toff = ((t / 4 - 1) * W2 + (t % 4 - 1)) * ICP + ks * 32;
#pragma unroll
      for (int nt = 0; nt < NTN; nt++) {
        uint4 bf = *reinterpret_cast<const uint4*>(&sIn[base[nt] + toff]);
        acc[nt] = __builtin_amdgcn_mfma_f32_16x16x32_bf16(u2s(af[t]), u2s(bf),
                                                          acc[nt], 0, 0, 0);
      }
    }
  }
  float b4[4];
#pragma unroll
  for (int r = 0; r < 4; r++) b4[r] = bias[w * 16 + q * 4 + r];
#pragma unroll
  for (int nt = 0; nt < NTN; nt++) {
    const int px = nt * 16 + n;
#pragma unroll
    for (int r = 0; r < 4; r++)
      sOutT[px * OCP + (w * 16 + q * 4 + r)] = f2bf(fmaxf(acc[nt][r] + b4[r], 0.f));
  }
  __syncthreads();
  {
    unsigned short* yf = yout + (size_t)f * NPO * OC;
    for (int i = tid; i < NPO * (OC / 8); i += 256) {
      const int px = i / (OC / 8), g = i - px * (OC / 8);
      uint4 v = *reinterpret_cast<const uint4*>(&sOutT[px * OCP + g * 8]);
      *reinterpret_cast<uint4*>(yf + px * OC + g * 8) = v;
    }
  }
}

// ==================== MFMA deconv (ConvTranspose2d k4 s2 p1, relu) =========
template<int IC, int IH, int IW, int OC, int OUTBF>
__global__ __launch_bounds__(256, 2) void k_deconv_mfma(
    const unsigned short* __restrict__ xin,
    const unsigned short* __restrict__ wpk,
    const float* __restrict__ bias,
    unsigned short* __restrict__ ybf, float* __restrict__ yfp) {
  constexpr int OH = 2 * IH, OW = 2 * IW;
  constexpr int NPC = IH * IW, NTN = NPC / 16, MT = OC / 16;
  constexpr int MTL = (NTN == 1) ? 1 : MT;
  constexpr int ICP = IC + 8, KS = IC / 32;
  constexpr int W2 = IW + 2, H2 = IH + 2, OCP = OC + 8;
  __shared__ __align__(16) unsigned short sIn[H2 * W2 * ICP];
  __shared__ __align__(16) unsigned short sOutT[OUTBF ? OH * OW * OCP : 16];
  const int f = blockIdx.x, tid = threadIdx.x;
  const int w = tid >> 6, l = tid & 63, q = l >> 4, n = l & 15;
  const int nt = (NTN == 1) ? 0 : w;
  const int mt0 = (NTN == 1) ? w : 0;
  {
    unsigned int* z = (unsigned int*)sIn;
    for (int i = tid; i < H2 * W2 * ICP / 2; i += 256) z[i] = 0u;
  }
  __syncthreads();
  {
    const unsigned short* xf = xin + (size_t)f * IH * IW * IC;
    for (int i = tid; i < IH * IW * (IC / 8); i += 256) {
      const int px = i / (IC / 8), g = i - px * (IC / 8);
      const int iy = px / IW, ix = px - iy * IW;
      uint4 v = *reinterpret_cast<const uint4*>(xf + px * IC + g * 8);
      *reinterpret_cast<uint4*>(&sIn[((iy + 1) * W2 + (ix + 1)) * ICP + g * 8]) = v;
    }
  }
  __syncthreads();
  const int px = nt * 16 + n;
  const int Y = px / IW, X = px - Y * IW;
  const int ibase = ((Y + 1) * W2 + (X + 1)) * ICP + q * 8;
  float b4[MTL][4];
#pragma unroll
  for (int mi = 0; mi < MTL; mi++)
#pragma unroll
    for (int r = 0; r < 4; r++) b4[mi][r] = bias[(mt0 + mi) * 16 + q * 4 + r];
#pragma unroll
  for (int c = 0; c < 4; c++) {
    const int cy = c >> 1, cx = c & 1;
    floatx4 acc[MTL];
#pragma unroll
    for (int mi = 0; mi < MTL; mi++) acc[mi] = (floatx4){0.f, 0.f, 0.f, 0.f};
    for (int ks = 0; ks < KS; ks++) {
      uint4 af[MTL][4];
#pragma unroll
      for (int mi = 0; mi < MTL; mi++)
#pragma unroll
        for (int tt = 0; tt < 4; tt++) {
          const int t2 = tt >> 1, t3 = tt & 1;
          const int ky = ((cy + 1) & 1) + 2 * t2, kx = ((cx + 1) & 1) + 2 * t3;
          af[mi][tt] = *reinterpret_cast<const uint4*>(
              wpk + ((size_t)((ky * 4 + kx) * OC + (mt0 + mi) * 16 + n) * IC +
                     ks * 32 + q * 8));
        }
#pragma unroll
      for (int tt = 0; tt < 4; tt++) {
        const int t2 = tt >> 1, t3 = tt & 1;
        const int toff = ((cy - t2) * W2 + (cx - t3)) * ICP + ks * 32;
        uint4 bf = *reinterpret_cast<const uint4*>(&sIn[ibase + toff]);
#pragma unroll
        for (int mi = 0; mi < MTL; mi++)
          acc[mi] = __builtin_amdgcn_mfma_f32_16x16x32_bf16(u2s(af[mi][tt]),
                                                            u2s(bf), acc[mi], 0, 0, 0);
      }
    }
    const int oy = 2 * Y + cy, ox = 2 * X + cx, opx = oy * OW + ox;
#pragma unroll
    for (int mi = 0; mi < MTL; mi++)
#pragma unroll
      for (int r = 0; r < 4; r++) {
        const int oc = (mt0 + mi) * 16 + q * 4 + r;
        const float v = fmaxf(acc[mi][r] + b4[mi][r], 0.f);
        if (OUTBF) sOutT[opx * OCP + oc] = f2bf(v);
        else yfp[(size_t)f * OC * OH * OW + oc * OH * OW + opx] = v;
      }
  }
  if (OUTBF) {
    __syncthreads();
    unsigned short* yf = ybf + (size_t)f * OH * OW * OC;
    for (int i = tid; i < OH * OW * (OC / 8); i += 256) {
      const int p2 = i / (OC / 8), g = i - p2 * (OC / 8);
      uint4 v = *reinterpret_cast<const uint4*>(&sOutT[p2 * OCP + g * 8]);
      *reinterpret_cast<uint4*>(yf + p2 * OC + g * 8) = v;
    }
  }
}

// ==================== deconv3 (fp32 VALU, sigmoid, REMAP) ==================
template<int IC, int IH, int IW, int OC, int TOC, int TPX, int CH, int ACT, int REMAP>
__global__ __launch_bounds__(256) void k_deconv_s2(const float* __restrict__ x,
    const float* __restrict__ w, const float* __restrict__ bias,
    float* __restrict__ y) {
  constexpr int OH = IH * 2, OW = IW * 2, NPX = OH * OW;
  constexpr int IWP = IW + 1, OCP = OC + 1;
  constexpr int NQ = (OW / 2) / TPX;
  constexpr int NPXG = OH * 2 * NQ;
  static_assert((OC / TOC) * NPXG == 256, "thread mapping");
  __shared__ float sIn[IC * IH * IWP];
  __shared__ float sW[CH * 16 * OCP];
  const int f = blockIdx.x, tid = threadIdx.x;
  const float* xf = x + (size_t)f * IC * IH * IW;
  for (int i = tid; i < IC * IH * IW; i += 256) {
    const int ic = i / (IH * IW), rem = i - ic * (IH * IW);
    sIn[ic * (IH * IWP) + (rem / IW) * IWP + rem % IW] = xf[i];
  }
  const int ocg = tid / NPXG, pxg = tid - ocg * NPXG;
  const int oc0 = ocg * TOC;
  const int oy = pxg / (2 * NQ);
  const int rem2 = pxg - oy * (2 * NQ);
  const int c = rem2 / NQ, q = rem2 - c * NQ;
  const int py = (oy + 1) & 1, pc = (c + 1) & 1;
  float acc[TOC][TPX];
#pragma unroll
  for (int a = 0; a < TOC; a++) {
    const float bv = bias[oc0 + a];
#pragma unroll
    for (int j = 0; j < TPX; j++) acc[a][j] = bv;
  }
  for (int icb = 0; icb < IC; icb += CH) {
    __syncthreads();
    {
      const float* wb = w + (size_t)icb * OC * 16;
      for (int s = tid; s < CH * OC * 16; s += 256) {
        const int icc = s / (OC * 16), r = s - icc * (OC * 16);
        const int oc = r / 16, tap = r & 15;
        sW[(icc * 16 + tap) * OCP + oc] = wb[s];
      }
    }
    __syncthreads();
    for (int icc = 0; icc < CH; icc++) {
      const float* inb = &sIn[(icb + icc) * (IH * IWP)];
      const float* wb = &sW[icc * 16 * OCP];
#pragma unroll
      for (int t2 = 0; t2 < 2; t2++) {
        const int ky = py + 2 * t2;
        const int iy = (oy + 1 - ky) >> 1;
        if (iy < 0 || iy >= IH) continue;
        const float* row = inb + iy * IWP;
#pragma unroll
        for (int t3 = 0; t3 < 2; t3++) {
          const int kx = pc + 2 * t3;
          const int ixb = (c + 1 - kx) >> 1;
          float wv[TOC];
#pragma unroll
          for (int a = 0; a < TOC; a++) wv[a] = wb[(ky * 4 + kx) * OCP + oc0 + a];
#pragma unroll
          for (int j = 0; j < TPX; j++) {
            const int ix = ixb + q * TPX + j;
            if (ix >= 0 && ix < IW) {
              const float xv = row[ix];
#pragma unroll
              for (int a = 0; a < TOC; a++) acc[a][j] += wv[a] * xv;
            }
          }
        }
      }
    }
  }
  int fo = f;
  if (REMAP) fo = (f & (NB - 1)) * NT + (f >> 5);
  float* yf = y + (size_t)fo * OC * NPX;
#pragma unroll
  for (int a = 0; a < TOC; a++)
#pragma unroll
    for (int j = 0; j < TPX; j++) {
      float v = acc[a][j];
      if (ACT == 1) v = fmaxf(v, 0.f);
      if (ACT == 2) v = 1.f / (1.f + expf(-v));
      yf[(oc0 + a) * NPX + oy * OW + (c + 2 * (q * TPX + j))] = v;
    }
}

// ==================== encoder linear: bf16 [f][16px][64c] -> emb fp32 ======
__global__ __launch_bounds__(256) void k_enclin(const unsigned short* __restrict__ x,
    const float* __restrict__ wT, const float* __restrict__ bias,
    float* __restrict__ emb) {
  __shared__ float sX[1024];
  __shared__ float sP[256];
  const int f = blockIdx.x, tid = threadIdx.x;
  if (tid < 128) {
    const int px = tid >> 3, g = tid & 7;
    uint4 v = *reinterpret_cast<const uint4*>(x + (size_t)f * 1024 + px * 64 + g * 8);
    const int c0 = g * 8;
    sX[(c0 + 0) * 16 + px] = __uint_as_float(v.x << 16);
    sX[(c0 + 1) * 16 + px] = __uint_as_float(v.x & 0xffff0000u);
    sX[(c0 + 2) * 16 + px] = __uint_as_float(v.y << 16);
    sX[(c0 + 3) * 16 + px] = __uint_as_float(v.y & 0xffff0000u);
    sX[(c0 + 4) * 16 + px] = __uint_as_float(v.z << 16);
    sX[(c0 + 5) * 16 + px] = __uint_as_float(v.z & 0xffff0000u);
    sX[(c0 + 6) * 16 + px] = __uint_as_float(v.w << 16);
    sX[(c0 + 7) * 16 + px] = __uint_as_float(v.w & 0xffff0000u);
  }
  __syncthreads();
  const int o = tid & 63, s = tid >> 6;
  float acc = 0.f;
  const int k0 = s * 256;
  for (int k = k0; k < k0 + 256; k++) acc += wT[k * 64 + o] * sX[k];
  sP[tid] = acc;
  __syncthreads();
  if (tid < 64)
    emb[(size_t)f * 64 + tid] =
        sP[tid] + sP[tid + 64] + sP[tid + 128] + sP[tid + 192] + bias[tid];
}

// ==================== precompute (coalesced via transposed weights) ========
__global__ __launch_bounds__(512) void k_pre(const float* __restrict__ emb,
    const float* __restrict__ act, const float* __restrict__ pw1T,
    const float* __restrict__ pb1, const float* __restrict__ wihT,
    const float* __restrict__ bih, float* __restrict__ posl1e,
    float* __restrict__ gia) {
  __shared__ float sE[64];
  __shared__ float sA2[2];
  const int f = blockIdx.x, tid = threadIdx.x;
  if (tid < 64) sE[tid] = emb[(size_t)f * 64 + tid];
  else if (tid < 66) sA2[tid - 64] = act[(size_t)f * 2 + (tid - 64)];
  __syncthreads();
  if (tid < 128) {
    float a = pb1[tid];
    for (int k = 0; k < 64; k++) a += pw1T[(128 + k) * 128 + tid] * sE[k];
    posl1e[(size_t)f * 128 + tid] = a;
  } else {
    const int j = tid - 128;  // 0..383
    gia[(size_t)f * 384 + j] =
        bih[j] + wihT[32 * 384 + j] * sA2[0] + wihT[33 * 384 + j] * sA2[1];
  }
}

// ==================== recurrent core: MFMA, 2 blocks x 16 batch cols =======
// Stage A: [L1pre(128); gh(384)] = W(512x128) @ Hbf(128x16)  -> 128 MFMA
// Stage B: L2 = Wp2 @ L1 (32) ; C: pm/pls = Wp3 @ L2 (16) ; D: gi = Wihz @ z (24)
__global__ __launch_bounds__(512, 2) void k_rssm6(
    const float* __restrict__ posl1e, const float* __restrict__ gia,
    const float* __restrict__ noise,
    const unsigned short* __restrict__ wp1h, const unsigned short* __restrict__ wp2,
    const unsigned short* __restrict__ wp3, const unsigned short* __restrict__ wwhh,
    const unsigned short* __restrict__ wihz,
    const float* __restrict__ pb2, const float* __restrict__ pb3,
    const float* __restrict__ bhh,
    float* __restrict__ hs, float* __restrict__ out) {
  const int base = blockIdx.x * 16;
  const int tid = threadIdx.x;
  const int w = tid >> 6, l = tid & 63, q = l >> 4, n = l & 15;
  const int mD0 = w * 48;
  const int fb = (base + n) * 64;          // f-index base for this lane's batch col
  const int nz = tid >> 5, sz = tid & 31;  // z-stage / E-stage batch map

  __shared__ __align__(16) unsigned short hbf[16 * 136];   // [batch][k] bf16
  __shared__ __align__(16) unsigned short l1bf[16 * 136];
  __shared__ __align__(16) unsigned short l2bf[16 * 136];
  __shared__ __align__(16) unsigned short zbf[16 * 40];
  __shared__ __align__(16) float sGh[16 * 388];            // [batch][row] fp32
  __shared__ __align__(16) float sGi[16 * 388];
  __shared__ __align__(16) float sH[16 * 132];
  __shared__ __align__(16) float pmls[16 * 68];

  // ---- preload weight A-fragments (constant across steps)
  uint4 wa[4][4], wb4[4], wc4[4], wd[3];
#pragma unroll
  for (int mt = 0; mt < 4; mt++) {
    const int gr = w * 64 + mt * 16 + n;   // 0..511
    const unsigned short* src = (gr < 128) ? (wp1h + gr * 128)
                                           : (wwhh + (size_t)(gr - 128) * 128);
#pragma unroll
    for (int kc = 0; kc < 4; kc++)
      wa[mt][kc] = *reinterpret_cast<const uint4*>(src + kc * 32 + q * 8);
  }
#pragma unroll
  for (int kc = 0; kc < 4; kc++)
    wb4[kc] = *reinterpret_cast<const uint4*>(wp2 + (w * 16 + n) * 128 + kc * 32 + q * 8);
  if (w < 4) {
#pragma unroll
    for (int kc = 0; kc < 4; kc++)
      wc4[kc] = *reinterpret_cast<const uint4*>(wp3 + (w * 16 + n) * 128 + kc * 32 + q * 8);
  }
#pragma unroll
  for (int jt = 0; jt < 3; jt++)
    wd[jt] = *reinterpret_cast<const uint4*>(wihz + (size_t)(mD0 + jt * 16 + n) * 32 + q * 8);

  F4 bA[4], bB, bC;
  if (w >= 2) {
#pragma unroll
    for (int mt = 0; mt < 4; mt++)
      bA[mt].v = *reinterpret_cast<const float4*>(bhh + w * 64 - 128 + mt * 16 + q * 4);
  }
  bB.v = *reinterpret_cast<const float4*>(pb2 + w * 16 + q * 4);
  if (w < 4) bC.v = *reinterpret_cast<const float4*>(pb3 + w * 16 + q * 4);

  // ---- init h = 0
  for (int i = tid; i < 1088; i += 512) reinterpret_cast<unsigned int*>(hbf)[i] = 0u;
  for (int i = tid; i < 2112; i += 512) sH[i] = 0.f;
  {
    float4 z4; z4.x = z4.y = z4.z = z4.w = 0.f;
    *reinterpret_cast<float4*>(hs + (size_t)(base + nz) * 128 + sz * 4) = z4;
  }

  for (int t = 0; t < 64; ++t) {
    __syncthreads();  // hbf/sH from prev step visible; prev LDS consumed
    // ---- current-step inputs (used later in the step; latency hidden)
    F4 pl1R[4], giaR[3];
    if (w < 2) {
#pragma unroll
      for (int mt = 0; mt < 4; mt++)
        pl1R[mt].v = *reinterpret_cast<const float4*>(
            posl1e + (size_t)(fb + t) * 128 + w * 64 + mt * 16 + q * 4);
    }
#pragma unroll
    for (int jt = 0; jt < 3; jt++)
      giaR[jt].v = *reinterpret_cast<const float4*>(
          gia + (size_t)(fb + t) * 384 + mD0 + jt * 16 + q * 4);
    const float epsR = noise[(size_t)(t * 32 + base + nz) * 32 + sz];

    // ---- stage A
    {
      uint4 hf[4];
#pragma unroll
      for (int kc = 0; kc < 4; kc++)
        hf[kc] = *reinterpret_cast<const uint4*>(&hbf[n * 136 + kc * 32 + q * 8]);
      floatx4 acc[4];
#pragma unroll
      for (int mt = 0; mt < 4; mt++) acc[mt] = (floatx4){0.f, 0.f, 0.f, 0.f};
#pragma unroll
      for (int kc = 0; kc < 4; kc++)
#pragma unroll
        for (int mt = 0; mt < 4; mt++)
          acc[mt] = __builtin_amdgcn_mfma_f32_16x16x32_bf16(u2s(wa[mt][kc]),
                                                            u2s(hf[kc]), acc[mt], 0, 0, 0);
      if (w < 2) {
#pragma unroll
        for (int mt = 0; mt < 4; mt++) {
          const int row0 = w * 64 + mt * 16 + q * 4;
          *reinterpret_cast<uint2*>(&l1bf[n * 136 + row0]) =
              pk4(eluf(acc[mt][0] + pl1R[mt].a[0]), eluf(acc[mt][1] + pl1R[mt].a[1]),
                  eluf(acc[mt][2] + pl1R[mt].a[2]), eluf(acc[mt][3] + pl1R[mt].a[3]));
        }
      } else {
#pragma unroll
        for (int mt = 0; mt < 4; mt++) {
          const int row0 = w * 64 - 128 + mt * 16 + q * 4;
          F4 o;
#pragma unroll
          for (int r = 0; r < 4; r++) o.a[r] = acc[mt][r] + bA[mt].a[r];
          *reinterpret_cast<float4*>(&sGh[n * 388 + row0]) = o.v;
        }
      }
    }
    __syncthreads();
    // ---- stage B
    {
      uint4 xf[4];
#pragma unroll
      for (int kc = 0; kc < 4; kc++)
        xf[kc] = *reinterpret_cast<const uint4*>(&l1bf[n * 136 + kc * 32 + q * 8]);
      floatx4 acc = (floatx4){0.f, 0.f, 0.f, 0.f};
#pragma unroll
      for (int kc = 0; kc < 4; kc++)
        acc = __builtin_amdgcn_mfma_f32_16x16x32_bf16(u2s(wb4[kc]), u2s(xf[kc]), acc, 0, 0, 0);
      const int row0 = w * 16 + q * 4;
      *reinterpret_cast<uint2*>(&l2bf[n * 136 + row0]) =
          pk4(eluf(acc[0] + bB.a[0]), eluf(acc[1] + bB.a[1]),
              eluf(acc[2] + bB.a[2]), eluf(acc[3] + bB.a[3]));
    }
    __syncthreads();
    // ---- stage C (waves 0-3)
    if (w < 4) {
      uint4 yf[4];
#pragma unroll
      for (int kc = 0; kc < 4; kc++)
        yf[kc] = *reinterpret_cast<const uint4*>(&l2bf[n * 136 + kc * 32 + q * 8]);
      floatx4 acc = (floatx4){0.f, 0.f, 0.f, 0.f};
#pragma unroll
      for (int kc = 0; kc < 4; kc++)
        acc = __builtin_amdgcn_mfma_f32_16x16x32_bf16(u2s(wc4[kc]), u2s(yf[kc]), acc, 0, 0, 0);
      const int row0 = w * 16 + q * 4;
      F4 o;
#pragma unroll
      for (int r = 0; r < 4; r++) o.a[r] = acc[r] + bC.a[r];
      *reinterpret_cast<float4*>(&pmls[n * 68 + row0]) = o.v;
    }
    __syncthreads();
    // ---- z sample + latent outputs
    {
      const float pm = pmls[nz * 68 + sz];
      float pls = fminf(fmaxf(pmls[nz * 68 + 32 + sz], -5.f), 2.f);
      const float z = pm + expf(pls) * epsR;
      zbf[nz * 40 + sz] = f2bf(z);
      const int o = ((base + nz) * 64 + t) * 32 + sz;
      out[OUT_ZS + o] = z;
      out[OUT_PM + o] = pm;
      out[OUT_PLS + o] = pls;
    }
    __syncthreads();
    // ---- stage D
    {
      const uint4 zf = *reinterpret_cast<const uint4*>(&zbf[n * 40 + q * 8]);
#pragma unroll
      for (int jt = 0; jt < 3; jt++) {
        floatx4 acc = (floatx4){0.f, 0.f, 0.f, 0.f};
        acc = __builtin_amdgcn_mfma_f32_16x16x32_bf16(u2s(wd[jt]), u2s(zf), acc, 0, 0, 0);
        const int row0 = mD0 + jt * 16 + q * 4;
        F4 o;
#pragma unroll
        for (int r = 0; r < 4; r++) o.a[r] = acc[r] + giaR[jt].a[r];
        *reinterpret_cast<float4*>(&sGi[n * 388 + row0]) = o.v;
      }
    }
    __syncthreads();
    // ---- stage E: gates + h update
    {
      const int r0 = sz * 4;
      const float* gi = &sGi[nz * 388];
      const float* gh = &sGh[nz * 388];
      F4 g0, g1, g2, h0, h1, h2, hp, hn;
      g0.v = *reinterpret_cast<const float4*>(gi + r0);
      g1.v = *reinterpret_cast<const float4*>(gi + 128 + r0);
      g2.v = *reinterpret_cast<const float4*>(gi + 256 + r0);
      h0.v = *reinterpret_cast<const float4*>(gh + r0);
      h1.v = *reinterpret_cast<const float4*>(gh + 128 + r0);
      h2.v = *reinterpret_cast<const float4*>(gh + 256 + r0);
      hp.v = *reinterpret_cast<const float4*>(&sH[nz * 132 + r0]);
#pragma unroll
      for (int j = 0; j < 4; j++) {
        const float r = sigm(g0.a[j] + h0.a[j]);
        const float u = sigm(g1.a[j] + h1.a[j]);
        const float nn = tanhf(g2.a[j] + r * h2.a[j]);
        hn.a[j] = (1.f - u) * nn + u * hp.a[j];
      }
      *reinterpret_cast<float4*>(&sH[nz * 132 + r0]) = hn.v;
      *reinterpret_cast<uint2*>(&hbf[nz * 136 + r0]) =
          pk4(hn.a[0], hn.a[1], hn.a[2], hn.a[3]);
      if (t < 63)
        *reinterpret_cast<float4*>(hs + ((size_t)(t + 1) * 32 + base + nz) * 128 + r0) = hn.v;
    }
  }
  __syncthreads();
  *reinterpret_cast<float4*>(out + OUT_HF + (size_t)(base + nz) * 128 + sz * 4) =
      *reinterpret_cast<const float4*>(&sH[nz * 132 + sz * 4]);
}

// ==================== prior chain (coalesced transposed weights) ===========
__global__ __launch_bounds__(128) void k_pri(const float* __restrict__ hs,
    const float* __restrict__ act,
    const float* __restrict__ qw1T, const float* __restrict__ qb1,
    const float* __restrict__ qw2T, const float* __restrict__ qb2,
    const float* __restrict__ qw3T, const float* __restrict__ qb3,
    float* __restrict__ out) {
  __shared__ float sV[128], sW[128];
  __shared__ float sA2[2];
  const int f = blockIdx.x, tid = threadIdx.x;
  const int t = f >> 5, b = f & 31;
  sV[tid] = hs[(size_t)f * 128 + tid];
  if (tid < 2) sA2[tid] = act[(size_t)(b * 64 + t) * 2 + tid];
  __syncthreads();
  {
    float a = qb1[tid];
    for (int k = 0; k < 128; k++) a += qw1T[k * 128 + tid] * sV[k];
    a += qw1T[128 * 128 + tid] * sA2[0] + qw1T[129 * 128 + tid] * sA2[1];
    sW[tid] = eluf(a);
  }
  __syncthreads();
  {
    float a = qb2[tid];
    for (int k = 0; k < 128; k++) a += qw2T[k * 128 + tid] * sW[k];
    sV[tid] = eluf(a);
  }
  __syncthreads();
  if (tid < 64) {
    float a = qb3[tid];
    for (int k = 0; k < 128; k++) a += qw3T[k * 64 + tid] * sV[k];
    const int o = (b * 64 + t) * 32;
    if (tid < 32) out[OUT_PRM + o + tid] = a;
    else out[OUT_PRLS + o + tid - 32] = fminf(fmaxf(a, -5.f), 2.f);
  }
}

// ==================== decoder linear -> bf16 [f][16px][64c] ================
__global__ __launch_bounds__(256) void k_declin(const float* __restrict__ hs,
    const float* __restrict__ zs, const float* __restrict__ wT,
    const float* __restrict__ bias, unsigned short* __restrict__ y) {
  __shared__ float sX[160];
  __shared__ unsigned short sY[16 * 72];
  const int f = blockIdx.x, tid = threadIdx.x;
  const int t = f >> 5, b = f & 31;
  if (tid < 128) sX[tid] = hs[(size_t)(t * 32 + b) * 128 + tid];
  else if (tid < 160) sX[tid] = zs[(size_t)(b * 64 + t) * 32 + (tid - 128)];
  __syncthreads();
  float acc[4];
#pragma unroll
  for (int i = 0; i < 4; i++) acc[i] = bias[i * 256 + tid];
  for (int k = 0; k < 160; k++) {
    const float xv = sX[k];
#pragma unroll
    for (int i = 0; i < 4; i++) acc[i] += wT[k * 1024 + i * 256 + tid] * xv;
  }
#pragma unroll
  for (int i = 0; i < 4; i++) {
    const int o = i * 256 + tid, c = o >> 4, px = o & 15;
    sY[px * 72 + c] = f2bf(acc[i]);
  }
  __syncthreads();
  if (tid < 128) {
    const int px = tid >> 3, g = tid & 7;
    uint4 v = *reinterpret_cast<const uint4*>(&sY[px * 72 + g * 8]);
    *reinterpret_cast<uint4*>(y + (size_t)f * 1024 + px * 64 + g * 8) = v;
  }
}

// ==================== launch ====================
extern "C" void kernel_launch(void* const* d_in, const int* in_sizes, int n_in,
                              void* d_out, int out_size, void* d_ws, size_t ws_size,
                              hipStream_t stream) {
  const float* obs = (const float*)d_in[0];
  const float* actions = (const float*)d_in[1];
  const float* noise = (const float*)d_in[2];
  const float* enc_w1 = (const float*)d_in[3];
  const float* enc_b1 = (const float*)d_in[4];
  const float* enc_w2 = (const float*)d_in[5];
  const float* enc_b2 = (const float*)d_in[6];
  const float* enc_w3 = (const float*)d_in[7];
  const float* enc_b3 = (const float*)d_in[8];
  const float* enc_pw = (const float*)d_in[9];
  const float* enc_pb = (const float*)d_in[10];
  const float* dec_pw = (const float*)d_in[11];
  const float* dec_pb = (const float*)d_in[12];
  const float* dec_w1 = (const float*)d_in[13];
  const float* dec_b1 = (const float*)d_in[14];
  const float* dec_w2 = (const float*)d_in[15];
  const float* dec_b2 = (const float*)d_in[16];
  const float* dec_w3 = (const float*)d_in[17];
  const float* dec_b3 = (const float*)d_in[18];
  const float* gru_wih = (const float*)d_in[19];
  const float* gru_whh = (const float*)d_in[20];
  const float* gru_bih = (const float*)d_in[21];
  const float* gru_bhh = (const float*)d_in[22];
  const float* pri_w1 = (const float*)d_in[23];
  const float* pri_b1 = (const float*)d_in[24];
  const float* pri_w2 = (const float*)d_in[25];
  const float* pri_b2 = (const float*)d_in[26];
  const float* pri_w3 = (const float*)d_in[27];
  const float* pri_b3 = (const float*)d_in[28];
  const float* pos_w1 = (const float*)d_in[29];
  const float* pos_b1 = (const float*)d_in[30];
  const float* pos_w2 = (const float*)d_in[31];
  const float* pos_b2 = (const float*)d_in[32];
  const float* pos_w3 = (const float*)d_in[33];
  const float* pos_b3 = (const float*)d_in[34];

  float* out = (float*)d_out;
  float* ws = (float*)d_ws;
  unsigned short* X1us = (unsigned short*)(ws + WS_X1);
  float* X1f = ws + WS_X1;
  unsigned short* X2us = (unsigned short*)(ws + WS_X2);
  unsigned short* X3us = (unsigned short*)(ws + WS_X3);
  float* EMB = ws + WS_EMB;
  float* HS = ws + WS_HS;
  float* POSL1E = ws + WS_POSL1E;
  float* GIA = ws + WS_GIA;
  unsigned short* WP1H = (unsigned short*)(ws + WS_WP1H);
  unsigned short* WP2 = (unsigned short*)(ws + WS_WP2);
  unsigned short* WP3 = (unsigned short*)(ws + WS_WP3);
  unsigned short* WWHH = (unsigned short*)(ws + WS_WWHH);
  unsigned short* WIHZ = (unsigned short*)(ws + WS_WIHZ);
  unsigned short* WC2 = (unsigned short*)(ws + WS_WC2);
  unsigned short* WC3 = (unsigned short*)(ws + WS_WC3);
  unsigned short* WD1 = (unsigned short*)(ws + WS_WD1);
  unsigned short* WD2 = (unsigned short*)(ws + WS_WD2);

  // unified prep: 7 fp32 transposes + 9 bf16 packs in one dispatch
  PPAll pp;
  pp.m[0]  = {enc_pw, ws + WS_ENCT, 64 * 1024, 10, 64, 1024};
  pp.m[1]  = {dec_pw, ws + WS_DECT, 1024 * 160, 10, 1024, 160};
  pp.m[2]  = {pri_w1, ws + WS_QW1T, 128 * 130, 10, 128, 130};
  pp.m[3]  = {pri_w2, ws + WS_QW2T, 128 * 128, 10, 128, 128};
  pp.m[4]  = {pri_w3, ws + WS_QW3T, 64 * 128, 10, 64, 128};
  pp.m[5]  = {pos_w1, ws + WS_PW1T, 128 * 192, 10, 128, 192};
  pp.m[6]  = {gru_wih, ws + WS_WIHT, 384 * 34, 10, 384, 34};
  pp.m[7]  = {pos_w1, WP1H, 128 * 128, 1, 0, 0};
  pp.m[8]  = {pos_w2, WP2, 128 * 128, 0, 0, 0};
  pp.m[9]  = {pos_w3, WP3, 64 * 128, 0, 0, 0};
  pp.m[10] = {gru_whh, WWHH, 384 * 128, 0, 0, 0};
  pp.m[11] = {gru_wih, WIHZ, 384 * 32, 2, 0, 0};
  pp.m[12] = {enc_w2, WC2, 16 * 64 * 32, 3, 64, 32};
  pp.m[13] = {enc_w3, WC3, 16 * 64 * 64, 3, 64, 64};
  pp.m[14] = {dec_w1, WD1, 16 * 64 * 64, 4, 64, 64};
  pp.m[15] = {dec_w2, WD2, 16 * 32 * 64, 4, 32, 64};
  hipLaunchKernelGGL(k_prep, dim3(32, 16), dim3(256), 0, stream, pp);

  // encoder
  k_conv1<<<NF, 256, 0, stream>>>(obs, enc_w1, enc_b1, X1us);
  k_conv_mfma<32, 16, 16, 64><<<NF, 256, 0, stream>>>(X1us, WC2, enc_b2, X2us);
  k_conv_mfma<64, 8, 8, 64><<<NF, 256, 0, stream>>>(X2us, WC3, enc_b3, X3us);
  k_enclin<<<NF, 256, 0, stream>>>(X3us, ws + WS_ENCT, enc_pb, EMB);

  // recurrence inputs + core + prior
  k_pre<<<NF, 512, 0, stream>>>(EMB, actions, ws + WS_PW1T, pos_b1,
                                ws + WS_WIHT, gru_bih, POSL1E, GIA);
  k_rssm6<<<2, 512, 0, stream>>>(POSL1E, GIA, noise, WP1H, WP2, WP3, WWHH, WIHZ,
                                 pos_b2, pos_b3, gru_bhh, HS, out);
  k_pri<<<NF, 128, 0, stream>>>(HS, actions, ws + WS_QW1T, pri_b1,
                                ws + WS_QW2T, pri_b2, ws + WS_QW3T, pri_b3, out);

  // decoder
  k_declin<<<NF, 256, 0, stream>>>(HS, out + OUT_ZS, ws + WS_DECT, dec_pb, X3us);
  k_deconv_mfma<64, 4, 4, 64, 1><<<NF, 256, 0, stream>>>(X3us, WD1, dec_b1, X2us, nullptr);
  k_deconv_mfma<64, 8, 8, 32, 0><<<NF, 256, 0, stream>>>(X2us, WD2, dec_b2, nullptr, X1f);
  k_deconv_s2<32, 16, 16, 1, 1, 4, 32, 2, 1><<<NF, 256, 0, stream>>>(X1f, dec_w3, dec_b3, out);
}

// Round 11
// 562.313 us; speedup vs baseline: 1.3356x; 1.3356x over previous
//
#include <hip/hip_runtime.h>
#include <math.h>

// ---------------- problem dims ----------------
#define NB 32
#define NT 64
#define NF 2048  // NB*NT frames

// ---------------- output float offsets ----------------
#define OUT_ZS    2097152
#define OUT_PRM   (OUT_ZS + 65536)
#define OUT_PRLS  (OUT_PRM + 65536)
#define OUT_PM    (OUT_PRLS + 65536)
#define OUT_PLS   (OUT_PM + 65536)
#define OUT_HF    (OUT_PLS + 65536)

// ---------------- workspace float offsets ----------------
#define WS_HS    27394048   // 64*32*128
#define WS_ENCT  27656192   // enc_pw^T (1024x64)
#define WS_DECT  27721728   // dec_pw^T (160x1024)
#define WS_WP1H  27885568   // 128x128 bf16
#define WS_WP2   27893760   // 128x128 bf16
#define WS_WP3   27901952   // 64x128 bf16
#define WS_WWHH  27906048   // 384x128 bf16
#define WS_WIHZ  27930624   // 384x32 bf16
#define WS_QW1T  27936768   // 130x128
#define WS_QW2T  27953408   // 128x128
#define WS_QW3T  27969792   // 128x64
#define WS_PW1T  27977984   // 192x128
#define WS_WIHT  28002560   // 34x384
#define WS_WC2   16777216   // 16*64*32 bf16
#define WS_WC3   (WS_WC2 + 16384)
#define WS_WD1   (WS_WC3 + 32768)
#define WS_WD2   (WS_WD1 + 32768)
#define WS_POSL1E 25165824  // 2048*128
#define WS_GIA    (WS_POSL1E + 262144)  // 2048*384

// ==================== helpers ====================
typedef __attribute__((ext_vector_type(8))) short short8;
typedef __attribute__((ext_vector_type(4))) float floatx4;
union U4S8 { uint4 u; short8 s; };
__device__ __forceinline__ short8 u2s(uint4 u) { U4S8 x; x.u = u; return x.s; }
__device__ __forceinline__ float eluf(float a) { return (a > 0.f) ? a : expm1f(a); }
__device__ __forceinline__ float sigm(float a) { return 1.f / (1.f + expf(-a)); }
__device__ __forceinline__ unsigned short f2bf(float f) {
  unsigned int u = __float_as_uint(f);
  u += 0x7fffu + ((u >> 16) & 1u);
  return (unsigned short)(u >> 16);
}
__device__ __forceinline__ float dotp8(uint4 u, const float* __restrict__ x) {
  float4 x0 = *reinterpret_cast<const float4*>(x);
  float4 x1 = *reinterpret_cast<const float4*>(x + 4);
  float acc;
  acc  = __uint_as_float(u.x << 16) * x0.x;
  acc += __uint_as_float(u.x & 0xffff0000u) * x0.y;
  acc += __uint_as_float(u.y << 16) * x0.z;
  acc += __uint_as_float(u.y & 0xffff0000u) * x0.w;
  acc += __uint_as_float(u.z << 16) * x1.x;
  acc += __uint_as_float(u.z & 0xffff0000u) * x1.y;
  acc += __uint_as_float(u.w << 16) * x1.z;
  acc += __uint_as_float(u.w & 0xffff0000u) * x1.w;
  return acc;
}

// ==================== unified prep: fp32 transposes + bf16 packs ===========
// mode 10: fp32 transpose dst[c*A+r]=src[r*B+c]
// mode 0: bf16 direct; 1: pos_w1 h-part; 2: wih z-part;
// mode 3: conv w [oc][ic][t]->[t][oc][ic]; 4: deconv w [ic][oc][t]->[t][oc][ic]
struct PP { const float* src; void* dst; int n; int mode; int A; int B; };
struct PPAll { PP m[16]; };

__global__ __launch_bounds__(256) void k_prep(PPAll a) {
  PP p = a.m[blockIdx.y];
  for (int i = blockIdx.x * 256 + threadIdx.x; i < p.n; i += gridDim.x * 256) {
    if (p.mode == 10) {
      const int r = i / p.B, c = i - r * p.B;
      ((float*)p.dst)[c * p.A + r] = p.src[i];
    } else {
      float v;
      if (p.mode == 0) v = p.src[i];
      else if (p.mode == 1) v = p.src[(i >> 7) * 192 + (i & 127)];
      else if (p.mode == 2) v = p.src[(i >> 5) * 34 + (i & 31)];
      else {
        const int ab = p.A * p.B;
        const int t = i / ab, rem = i - t * ab;
        const int oc = rem / p.B, ic = rem - oc * p.B;
        v = (p.mode == 3) ? p.src[(oc * p.B + ic) * 16 + t]
                          : p.src[(ic * p.A + oc) * 16 + t];
      }
      ((unsigned short*)p.dst)[i] = f2bf(v);
    }
  }
}

// ==================== fused encoder: conv1->conv2->conv3->enclin->pre ======
// one block per frame f = b*64+t ; all activations LDS-resident.
__global__ __launch_bounds__(256, 2) void k_enc(
    const float* __restrict__ obs, const float* __restrict__ act,
    const float* __restrict__ w1, const float* __restrict__ b1,
    const unsigned short* __restrict__ wc2, const float* __restrict__ b2,
    const unsigned short* __restrict__ wc3, const float* __restrict__ b3,
    const float* __restrict__ encT, const float* __restrict__ encb,
    const float* __restrict__ pw1T, const float* __restrict__ pb1,
    const float* __restrict__ wihT, const float* __restrict__ bih,
    float* __restrict__ posl1e, float* __restrict__ gia) {
  const int f = blockIdx.x, tid = threadIdx.x;
  const int w = tid >> 6, l = tid & 63, q = l >> 4, n = l & 15;
  __shared__ float sIn1[32 * 33];
  __shared__ float sW1[512];
  __shared__ float sB1[32];
  __shared__ __align__(16) unsigned short sIn2[18 * 18 * 40];  // conv2 haloed in
  __shared__ __align__(16) unsigned short sIn3[10 * 10 * 72];  // conv3 haloed in
  __shared__ __align__(16) float sXe[1024];                    // enclin in [ch*16+px]
  __shared__ float sP[256];
  __shared__ float sE[64];
  __shared__ float sA2[2];

  // ---- stage conv1 inputs + zero haloed buffers
  {
    const float* in = obs + (size_t)f * 1024;
    for (int i = tid; i < 1024; i += 256) sIn1[(i >> 5) * 33 + (i & 31)] = in[i];
    for (int i = tid; i < 512; i += 256) sW1[i] = w1[i];
    if (tid < 32) sB1[tid] = b1[tid];
    if (tid < 2) sA2[tid] = act[(size_t)f * 2 + tid];
    unsigned int* z2 = (unsigned int*)sIn2;
    for (int i = tid; i < 18 * 18 * 40 / 2; i += 256) z2[i] = 0u;
    unsigned int* z3 = (unsigned int*)sIn3;
    for (int i = tid; i < 10 * 10 * 72 / 2; i += 256) z3[i] = 0u;
  }
  __syncthreads();
  // ---- conv1 (fp32) -> sIn2 interior
  for (int r = tid; r < 512; r += 256) {       // r = oc*16 + oy
    const int oc = r >> 4, oy = r & 15;
    float acc[16];
    const float bv = sB1[oc];
#pragma unroll
    for (int j = 0; j < 16; j++) acc[j] = bv;
#pragma unroll
    for (int ky = 0; ky < 4; ky++) {
      const int iy = 2 * oy + ky - 1;
      if (iy < 0 || iy >= 32) continue;
#pragma unroll
      for (int kx = 0; kx < 4; kx++) {
        const float wv = sW1[oc * 16 + ky * 4 + kx];
#pragma unroll
        for (int j = 0; j < 16; j++) {
          const int ix = 2 * j + kx - 1;
          if (ix >= 0 && ix < 32) acc[j] += wv * sIn1[iy * 33 + ix];
        }
      }
    }
#pragma unroll
    for (int j = 0; j < 16; j++)
      sIn2[((oy + 1) * 18 + (j + 1)) * 40 + oc] = f2bf(fmaxf(acc[j], 0.f));
  }
  __syncthreads();
  // ---- conv2 MFMA (IC=32 OC=64, 16x16 out) -> sIn3 interior
  {
    int base[4];
#pragma unroll
    for (int nt = 0; nt < 4; nt++) {
      const int px = nt * 16 + n, oy = px >> 3, ox = px & 7;
      base[nt] = ((2 * oy + 1) * 18 + (2 * ox + 1)) * 40 + q * 8;
    }
    floatx4 acc[4];
#pragma unroll
    for (int nt = 0; nt < 4; nt++) acc[nt] = (floatx4){0.f, 0.f, 0.f, 0.f};
    uint4 af[16];
#pragma unroll
    for (int t = 0; t < 16; t++)
      af[t] = *reinterpret_cast<const uint4*>(wc2 + (size_t)(t * 64 + w * 16 + n) * 32 + q * 8);
#pragma unroll
    for (int t = 0; t < 16; t++) {
      const int toff = ((t / 4 - 1) * 18 + (t % 4 - 1)) * 40;
#pragma unroll
      for (int nt = 0; nt < 4; nt++) {
        uint4 bf = *reinterpret_cast<const uint4*>(&sIn2[base[nt] + toff]);
        acc[nt] = __builtin_amdgcn_mfma_f32_16x16x32_bf16(u2s(af[t]), u2s(bf), acc[nt], 0, 0, 0);
      }
    }
    float b4[4];
#pragma unroll
    for (int r = 0; r < 4; r++) b4[r] = b2[w * 16 + q * 4 + r];
    __syncthreads();  // conv1's sIn2 reads complete everywhere before... (reads above done)
#pragma unroll
    for (int nt = 0; nt < 4; nt++) {
      const int px = nt * 16 + n, oy = px >> 3, ox = px & 7;
#pragma unroll
      for (int r = 0; r < 4; r++)
        sIn3[((oy + 1) * 10 + (ox + 1)) * 72 + (w * 16 + q * 4 + r)] =
            f2bf(fmaxf(acc[nt][r] + b4[r], 0.f));
    }
  }
  __syncthreads();
  // ---- conv3 MFMA (IC=64 OC=64, 4x4 out) -> sXe fp32 [ch*16+px]
  {
    const int oy = n >> 2, ox = n & 3;
    const int ibase = ((2 * oy + 1) * 10 + (2 * ox + 1)) * 72 + q * 8;
    floatx4 acc = (floatx4){0.f, 0.f, 0.f, 0.f};
    for (int ks = 0; ks < 2; ks++) {
      uint4 af[16];
#pragma unroll
      for (int t = 0; t < 16; t++)
        af[t] = *reinterpret_cast<const uint4*>(
            wc3 + (size_t)(t * 64 + w * 16 + n) * 64 + ks * 32 + q * 8);
#pragma unroll
      for (int t = 0; t < 16; t++) {
        const int toff = ((t / 4 - 1) * 10 + (t % 4 - 1)) * 72 + ks * 32;
        uint4 bf = *reinterpret_cast<const uint4*>(&sIn3[ibase + toff]);
        acc = __builtin_amdgcn_mfma_f32_16x16x32_bf16(u2s(af[t]), u2s(bf), acc, 0, 0, 0);
      }
    }
#pragma unroll
    for (int r = 0; r < 4; r++) {
      const int ch = w * 16 + q * 4 + r;
      sXe[ch * 16 + n] = fmaxf(acc[r] + b3[ch], 0.f);
    }
  }
  __syncthreads();
  // ---- enclin -> sE[64]
  {
    const int o = tid & 63, s = tid >> 6;
    float acc = 0.f;
    const int k0 = s * 256;
    for (int k = k0; k < k0 + 256; k++) acc += encT[k * 64 + o] * sXe[k];
    sP[tid] = acc;
  }
  __syncthreads();
  if (tid < 64)
    sE[tid] = sP[tid] + sP[tid + 64] + sP[tid + 128] + sP[tid + 192] + encb[tid];
  __syncthreads();
  // ---- pre: posl1e (e-part) + gia (a-part)
  if (tid < 128) {
    float a = pb1[tid];
    for (int k = 0; k < 64; k++) a += pw1T[(128 + k) * 128 + tid] * sE[k];
    posl1e[(size_t)f * 128 + tid] = a;
  } else {
#pragma unroll
    for (int jj = 0; jj < 3; jj++) {
      const int j = (tid - 128) + jj * 128;
      gia[(size_t)f * 384 + j] =
          bih[j] + wihT[32 * 384 + j] * sA2[0] + wihT[33 * 384 + j] * sA2[1];
    }
  }
}

// ==================== recurrent core (round-9 winner) ======================
__global__ __launch_bounds__(512, 2) void k_rssm4(
    const float* __restrict__ posl1e, const float* __restrict__ gia,
    const float* __restrict__ noise,
    const unsigned short* __restrict__ wp1h, const unsigned short* __restrict__ wp2,
    const unsigned short* __restrict__ wp3, const unsigned short* __restrict__ wwhh,
    const unsigned short* __restrict__ wihz,
    const float* __restrict__ pb2, const float* __restrict__ pb3,
    const float* __restrict__ bhh,
    float* __restrict__ hs, float* __restrict__ out) {
  const int b = blockIdx.x, tid = threadIdx.x;
  __shared__ __align__(16) float sH[128], sL1[128], sL2[128];
  __shared__ __align__(16) float sGh[384], sGi[384], sZ[32];
  __shared__ __align__(16) float sPart[512];
  uint4 wA[16], wB[4], wC[2], wD[4];
  {
    const unsigned short* rowA =
        (tid < 128) ? (wp1h + tid * 128) : (wwhh + (size_t)(tid - 128) * 128);
#pragma unroll
    for (int i = 0; i < 16; i++) wA[i] = reinterpret_cast<const uint4*>(rowA)[i];
    const unsigned short* rowB = wp2 + (tid & 127) * 128 + (tid >> 7) * 32;
#pragma unroll
    for (int i = 0; i < 4; i++) wB[i] = reinterpret_cast<const uint4*>(rowB)[i];
    const unsigned short* rowC = wp3 + (tid & 63) * 128 + (tid >> 6) * 16;
#pragma unroll
    for (int i = 0; i < 2; i++) wC[i] = reinterpret_cast<const uint4*>(rowC)[i];
    if (tid < 384) {
      const unsigned short* rowD = wihz + (size_t)tid * 32;
#pragma unroll
      for (int i = 0; i < 4; i++) wD[i] = reinterpret_cast<const uint4*>(rowD)[i];
    }
  }
  const float bhhR = (tid >= 128) ? bhh[tid - 128] : 0.f;
  const float pb2R = (tid < 128) ? pb2[tid] : 0.f;
  const float pb3mR = (tid < 32) ? pb3[tid] : 0.f;
  const float pb3sR = (tid < 32) ? pb3[tid + 32] : 0.f;
  float pl1R = 0.f, giaR = 0.f, epsR = 0.f;
  if (tid < 128) {
    pl1R = posl1e[(size_t)(b * 64) * 128 + tid];
    sH[tid] = 0.f;
    hs[(size_t)b * 128 + tid] = 0.f;
  }
  if (tid < 384) giaR = gia[(size_t)(b * 64) * 384 + tid];
  if (tid < 32) epsR = noise[(size_t)b * 32 + tid];

  for (int t = 0; t < 64; ++t) {
    __syncthreads();
    const int tn = (t < 63) ? t + 1 : 63;
    float pl1N = 0.f, giaN = 0.f, epsN = 0.f;
    if (tid < 128) pl1N = posl1e[(size_t)(b * 64 + tn) * 128 + tid];
    if (tid < 384) giaN = gia[(size_t)(b * 64 + tn) * 384 + tid];
    if (tid < 32) epsN = noise[(size_t)(tn * 32 + b) * 32 + tid];
    {
      float a = (tid < 128) ? pl1R : bhhR;
#pragma unroll
      for (int i = 0; i < 16; i++) a += dotp8(wA[i], sH + i * 8);
      if (tid < 128) sL1[tid] = eluf(a);
      else sGh[tid - 128] = a;
    }
    __syncthreads();
    {
      const float* xb = sL1 + (tid >> 7) * 32;
      float p = 0.f;
#pragma unroll
      for (int i = 0; i < 4; i++) p += dotp8(wB[i], xb + i * 8);
      sPart[tid] = p;
    }
    __syncthreads();
    if (tid < 128)
      sL2[tid] = eluf(pb2R + sPart[tid] + sPart[tid + 128] + sPart[tid + 256] +
                      sPart[tid + 384]);
    __syncthreads();
    {
      const float* xc = sL2 + (tid >> 6) * 16;
      sPart[tid] = dotp8(wC[0], xc) + dotp8(wC[1], xc + 8);
    }
    __syncthreads();
    if (tid < 32) {
      float pm = pb3mR, pls = pb3sR;
#pragma unroll
      for (int c = 0; c < 8; c++) {
        pm += sPart[c * 64 + tid];
        pls += sPart[c * 64 + 32 + tid];
      }
      pls = fminf(fmaxf(pls, -5.f), 2.f);
      const float z = pm + expf(pls) * epsR;
      sZ[tid] = z;
      const int o = (b * 64 + t) * 32 + tid;
      out[OUT_ZS + o] = z;
      out[OUT_PM + o] = pm;
      out[OUT_PLS + o] = pls;
    }
    __syncthreads();
    if (tid < 384) {
      float s = giaR;
#pragma unroll
      for (int i = 0; i < 4; i++) s += dotp8(wD[i], sZ + i * 8);
      sGi[tid] = s;
    }
    __syncthreads();
    if (tid < 128) {
      const float r = sigm(sGi[tid] + sGh[tid]);
      const float u = sigm(sGi[128 + tid] + sGh[128 + tid]);
      const float n = tanhf(sGi[256 + tid] + r * sGh[256 + tid]);
      const float hn = (1.f - u) * n + u * sH[tid];
      sH[tid] = hn;
      if (t < 63) hs[(size_t)((t + 1) * 32 + b) * 128 + tid] = hn;
    }
    pl1R = pl1N;
    giaR = giaN;
    epsR = epsN;
  }
  __syncthreads();
  if (tid < 128) out[OUT_HF + b * 128 + tid] = sH[tid];
}

// ==================== prior chain (coalesced transposed weights) ===========
__global__ __launch_bounds__(128) void k_pri(const float* __restrict__ hs,
    const float* __restrict__ act,
    const float* __restrict__ qw1T, const float* __restrict__ qb1,
    const float* __restrict__ qw2T, const float* __restrict__ qb2,
    const float* __restrict__ qw3T, const float* __restrict__ qb3,
    float* __restrict__ out) {
  __shared__ float sV[128], sW[128];
  __shared__ float sA2[2];
  const int f = blockIdx.x, tid = threadIdx.x;
  const int t = f >> 5, b = f & 31;
  sV[tid] = hs[(size_t)f * 128 + tid];
  if (tid < 2) sA2[tid] = act[(size_t)(b * 64 + t) * 2 + tid];
  __syncthreads();
  {
    float a = qb1[tid];
    for (int k = 0; k < 128; k++) a += qw1T[k * 128 + tid] * sV[k];
    a += qw1T[128 * 128 + tid] * sA2[0] + qw1T[129 * 128 + tid] * sA2[1];
    sW[tid] = eluf(a);
  }
  __syncthreads();
  {
    float a = qb2[tid];
    for (int k = 0; k < 128; k++) a += qw2T[k * 128 + tid] * sW[k];
    sV[tid] = eluf(a);
  }
  __syncthreads();
  if (tid < 64) {
    float a = qb3[tid];
    for (int k = 0; k < 128; k++) a += qw3T[k * 64 + tid] * sV[k];
    const int o = (b * 64 + t) * 32;
    if (tid < 32) out[OUT_PRM + o + tid] = a;
    else out[OUT_PRLS + o + tid - 32] = fminf(fmaxf(a, -5.f), 2.f);
  }
}

// ==================== fused decoder: declin->deconv1->deconv2->deconv3 =====
// one block per frame f = t*32+b ; all activations LDS-resident.
__global__ __launch_bounds__(256, 2) void k_dec(
    const float* __restrict__ hs, const float* __restrict__ zs,
    const float* __restrict__ decT, const float* __restrict__ decb,
    const unsigned short* __restrict__ wd1, const float* __restrict__ db1,
    const unsigned short* __restrict__ wd2, const float* __restrict__ db2,
    const float* __restrict__ w3, const float* __restrict__ b3,
    float* __restrict__ out) {
  const int f = blockIdx.x, tid = threadIdx.x;
  const int w = tid >> 6, l = tid & 63, q = l >> 4, n = l & 15;
  const int t = f >> 5, b = f & 31;
  __shared__ float sX[160];
  __shared__ __align__(16) unsigned short sInD1[6 * 6 * 72];    // deconv1 haloed in
  __shared__ __align__(16) unsigned short sInD2[10 * 10 * 72];  // deconv2 haloed in
  __shared__ float sInD3[32 * 16 * 17];                         // deconv3 in [ic][iy][ix+pad]
  __shared__ float sW3[32 * 16 * 2];

  // ---- stage inputs + zero halos + stage deconv3 weights
  if (tid < 128) sX[tid] = hs[(size_t)f * 128 + tid];
  else if (tid < 160) sX[tid] = zs[(size_t)(b * 64 + t) * 32 + (tid - 128)];
  {
    unsigned int* z1 = (unsigned int*)sInD1;
    for (int i = tid; i < 6 * 6 * 72 / 2; i += 256) z1[i] = 0u;
    unsigned int* z2 = (unsigned int*)sInD2;
    for (int i = tid; i < 10 * 10 * 72 / 2; i += 256) z2[i] = 0u;
    for (int s = tid; s < 512; s += 256) {
      const int icc = s >> 4, tap = s & 15;
      sW3[(icc * 16 + tap) * 2] = w3[s];
    }
  }
  __syncthreads();
  // ---- declin (fp32, K=160) -> sInD1 interior, bf16
  {
    float acc[4];
#pragma unroll
    for (int i = 0; i < 4; i++) acc[i] = decb[i * 256 + tid];
    for (int k = 0; k < 160; k++) {
      const float xv = sX[k];
#pragma unroll
      for (int i = 0; i < 4; i++) acc[i] += decT[k * 1024 + i * 256 + tid] * xv;
    }
#pragma unroll
    for (int i = 0; i < 4; i++) {
      const int o = i * 256 + tid, c = o >> 4, px = o & 15;
      const int Y = px >> 2, X = px & 3;
      sInD1[((Y + 1) * 6 + (X + 1)) * 72 + c] = f2bf(acc[i]);
    }
  }
  __syncthreads();
  // ---- deconv1 MFMA (IC=64 IH=IW=4 OC=64) -> sInD2 interior
  {
    const int Y = n >> 2, X = n & 3;
    const int ibase = ((Y + 1) * 6 + (X + 1)) * 72 + q * 8;
    float b4[4];
#pragma unroll
    for (int r = 0; r < 4; r++) b4[r] = db1[w * 16 + q * 4 + r];
#pragma unroll
    for (int c = 0; c < 4; c++) {
      const int cy = c >> 1, cx = c & 1;
      floatx4 acc = (floatx4){0.f, 0.f, 0.f, 0.f};
      for (int ks = 0; ks < 2; ks++) {
        uint4 af[4];
#pragma unroll
        for (int tt = 0; tt < 4; tt++) {
          const int t2 = tt >> 1, t3 = tt & 1;
          const int ky = ((cy + 1) & 1) + 2 * t2, kx = ((cx + 1) & 1) + 2 * t3;
          af[tt] = *reinterpret_cast<const uint4*>(
              wd1 + (size_t)((ky * 4 + kx) * 64 + w * 16 + n) * 64 + ks * 32 + q * 8);
        }
#pragma unroll
        for (int tt = 0; tt < 4; tt++) {
          const int t2 = tt >> 1, t3 = tt & 1;
          const int toff = ((cy - t2) * 6 + (cx - t3)) * 72 + ks * 32;
          uint4 bf = *reinterpret_cast<const uint4*>(&sInD1[ibase + toff]);
          acc = __builtin_amdgcn_mfma_f32_16x16x32_bf16(u2s(af[tt]), u2s(bf), acc, 0, 0, 0);
        }
      }
      const int oy = 2 * Y + cy, ox = 2 * X + cx;
#pragma unroll
      for (int r = 0; r < 4; r++)
        sInD2[((oy + 1) * 10 + (ox + 1)) * 72 + (w * 16 + q * 4 + r)] =
            f2bf(fmaxf(acc[r] + b4[r], 0.f));
    }
  }
  __syncthreads();
  // ---- deconv2 MFMA (IC=64 IH=IW=8 OC=32) -> sInD3 fp32
  {
    const int px = w * 16 + n;
    const int Y = px >> 3, X = px & 7;
    const int ibase = ((Y + 1) * 10 + (X + 1)) * 72 + q * 8;
    float b4[2][4];
#pragma unroll
    for (int mi = 0; mi < 2; mi++)
#pragma unroll
      for (int r = 0; r < 4; r++) b4[mi][r] = db2[mi * 16 + q * 4 + r];
#pragma unroll
    for (int c = 0; c < 4; c++) {
      const int cy = c >> 1, cx = c & 1;
      floatx4 acc[2];
      acc[0] = (floatx4){0.f, 0.f, 0.f, 0.f};
      acc[1] = (floatx4){0.f, 0.f, 0.f, 0.f};
      for (int ks = 0; ks < 2; ks++) {
        uint4 af[2][4];
#pragma unroll
        for (int mi = 0; mi < 2; mi++)
#pragma unroll
          for (int tt = 0; tt < 4; tt++) {
            const int t2 = tt >> 1, t3 = tt & 1;
            const int ky = ((cy + 1) & 1) + 2 * t2, kx = ((cx + 1) & 1) + 2 * t3;
            af[mi][tt] = *reinterpret_cast<const uint4*>(
                wd2 + (size_t)((ky * 4 + kx) * 32 + mi * 16 + n) * 64 + ks * 32 + q * 8);
          }
#pragma unroll
        for (int tt = 0; tt < 4; tt++) {
          const int t2 = tt >> 1, t3 = tt & 1;
          const int toff = ((cy - t2) * 10 + (cx - t3)) * 72 + ks * 32;
          uint4 bf = *reinterpret_cast<const uint4*>(&sInD2[ibase + toff]);
#pragma unroll
          for (int mi = 0; mi < 2; mi++)
            acc[mi] = __builtin_amdgcn_mfma_f32_16x16x32_bf16(u2s(af[mi][tt]), u2s(bf),
                                                              acc[mi], 0, 0, 0);
        }
      }
      const int oy = 2 * Y + cy, ox = 2 * X + cx;
#pragma unroll
      for (int mi = 0; mi < 2; mi++)
#pragma unroll
        for (int r = 0; r < 4; r++) {
          const int oc = mi * 16 + q * 4 + r;
          sInD3[oc * 272 + oy * 17 + ox] = fmaxf(acc[mi][r] + b4[mi][r], 0.f);
        }
    }
  }
  __syncthreads();
  // ---- deconv3 (fp32, OC=1, sigmoid, REMAP) from sInD3
  {
    const int oy = tid >> 3;               // 0..31
    const int rem2 = tid & 7;
    const int cpar = rem2 >> 2, qq = rem2 & 3;
    const int py = (oy + 1) & 1, pc = (cpar + 1) & 1;
    float acc[4];
    const float bv = b3[0];
#pragma unroll
    for (int j = 0; j < 4; j++) acc[j] = bv;
    for (int icc = 0; icc < 32; icc++) {
      const float* inb = &sInD3[icc * 272];
      const float* wb = &sW3[icc * 32];
#pragma unroll
      for (int t2 = 0; t2 < 2; t2++) {
        const int ky = py + 2 * t2;
        const int iy = (oy + 1 - ky) >> 1;
        if (iy < 0 || iy >= 16) continue;
        const float* row = inb + iy * 17;
#pragma unroll
        for (int t3 = 0; t3 < 2; t3++) {
          const int kx = pc + 2 * t3;
          const int ixb = (cpar + 1 - kx) >> 1;
          const float wv = wb[(ky * 4 + kx) * 2];
#pragma unroll
          for (int j = 0; j < 4; j++) {
            const int ix = ixb + qq * 4 + j;
            if (ix >= 0 && ix < 16) acc[j] += wv * row[ix];
          }
        }
      }
    }
    const int fo = b * 64 + t;  // REMAP (t*32+b -> b*64+t)
    float* yf = out + (size_t)fo * 1024;
#pragma unroll
    for (int j = 0; j < 4; j++)
      yf[oy * 32 + (cpar + 2 * (qq * 4 + j))] = 1.f / (1.f + expf(-acc[j]));
  }
}

// ==================== launch ====================
extern "C" void kernel_launch(void* const* d_in, const int* in_sizes, int n_in,
                              void* d_out, int out_size, void* d_ws, size_t ws_size,
                              hipStream_t stream) {
  const float* obs = (const float*)d_in[0];
  const float* actions = (const float*)d_in[1];
  const float* noise = (const float*)d_in[2];
  const float* enc_w1 = (const float*)d_in[3];
  const float* enc_b1 = (const float*)d_in[4];
  const float* enc_w2 = (const float*)d_in[5];
  const float* enc_b2 = (const float*)d_in[6];
  const float* enc_w3 = (const float*)d_in[7];
  const float* enc_b3 = (const float*)d_in[8];
  const float* enc_pw = (const float*)d_in[9];
  const float* enc_pb = (const float*)d_in[10];
  const float* dec_pw = (const float*)d_in[11];
  const float* dec_pb = (const float*)d_in[12];
  const float* dec_w1 = (const float*)d_in[13];
  const float* dec_b1 = (const float*)d_in[14];
  const float* dec_w2 = (const float*)d_in[15];
  const float* dec_b2 = (const float*)d_in[16];
  const float* dec_w3 = (const float*)d_in[17];
  const float* dec_b3 = (const float*)d_in[18];
  const float* gru_wih = (const float*)d_in[19];
  const float* gru_whh = (const float*)d_in[20];
  const float* gru_bih = (const float*)d_in[21];
  const float* gru_bhh = (const float*)d_in[22];
  const float* pri_w1 = (const float*)d_in[23];
  const float* pri_b1 = (const float*)d_in[24];
  const float* pri_w2 = (const float*)d_in[25];
  const float* pri_b2 = (const float*)d_in[26];
  const float* pri_w3 = (const float*)d_in[27];
  const float* pri_b3 = (const float*)d_in[28];
  const float* pos_w1 = (const float*)d_in[29];
  const float* pos_b1 = (const float*)d_in[30];
  const float* pos_w2 = (const float*)d_in[31];
  const float* pos_b2 = (const float*)d_in[32];
  const float* pos_w3 = (const float*)d_in[33];
  const float* pos_b3 = (const float*)d_in[34];

  float* out = (float*)d_out;
  float* ws = (float*)d_ws;
  float* HS = ws + WS_HS;
  float* POSL1E = ws + WS_POSL1E;
  float* GIA = ws + WS_GIA;
  unsigned short* WP1H = (unsigned short*)(ws + WS_WP1H);
  unsigned short* WP2 = (unsigned short*)(ws + WS_WP2);
  unsigned short* WP3 = (unsigned short*)(ws + WS_WP3);
  unsigned short* WWHH = (unsigned short*)(ws + WS_WWHH);
  unsigned short* WIHZ = (unsigned short*)(ws + WS_WIHZ);
  unsigned short* WC2 = (unsigned short*)(ws + WS_WC2);
  unsigned short* WC3 = (unsigned short*)(ws + WS_WC3);
  unsigned short* WD1 = (unsigned short*)(ws + WS_WD1);
  unsigned short* WD2 = (unsigned short*)(ws + WS_WD2);

  // unified prep: 7 fp32 transposes + 9 bf16 packs in one dispatch
  PPAll pp;
  pp.m[0]  = {enc_pw, ws + WS_ENCT, 64 * 1024, 10, 64, 1024};
  pp.m[1]  = {dec_pw, ws + WS_DECT, 1024 * 160, 10, 1024, 160};
  pp.m[2]  = {pri_w1, ws + WS_QW1T, 128 * 130, 10, 128, 130};
  pp.m[3]  = {pri_w2, ws + WS_QW2T, 128 * 128, 10, 128, 128};
  pp.m[4]  = {pri_w3, ws + WS_QW3T, 64 * 128, 10, 64, 128};
  pp.m[5]  = {pos_w1, ws + WS_PW1T, 128 * 192, 10, 128, 192};
  pp.m[6]  = {gru_wih, ws + WS_WIHT, 384 * 34, 10, 384, 34};
  pp.m[7]  = {pos_w1, WP1H, 128 * 128, 1, 0, 0};
  pp.m[8]  = {pos_w2, WP2, 128 * 128, 0, 0, 0};
  pp.m[9]  = {pos_w3, WP3, 64 * 128, 0, 0, 0};
  pp.m[10] = {gru_whh, WWHH, 384 * 128, 0, 0, 0};
  pp.m[11] = {gru_wih, WIHZ, 384 * 32, 2, 0, 0};
  pp.m[12] = {enc_w2, WC2, 16 * 64 * 32, 3, 64, 32};
  pp.m[13] = {enc_w3, WC3, 16 * 64 * 64, 3, 64, 64};
  pp.m[14] = {dec_w1, WD1, 16 * 64 * 64, 4, 64, 64};
  pp.m[15] = {dec_w2, WD2, 16 * 32 * 64, 4, 32, 64};
  hipLaunchKernelGGL(k_prep, dim3(32, 16), dim3(256), 0, stream, pp);

  // fused encoder (conv1..pre)
  k_enc<<<NF, 256, 0, stream>>>(obs, actions, enc_w1, enc_b1, WC2, enc_b2,
                                WC3, enc_b3, ws + WS_ENCT, enc_pb,
                                ws + WS_PW1T, pos_b1, ws + WS_WIHT, gru_bih,
                                POSL1E, GIA);

  // sequential core + prior
  k_rssm4<<<NB, 512, 0, stream>>>(POSL1E, GIA, noise, WP1H, WP2, WP3, WWHH, WIHZ,
                                  pos_b2, pos_b3, gru_bhh, HS, out);
  k_pri<<<NF, 128, 0, stream>>>(HS, actions, ws + WS_QW1T, pri_b1,
                                ws + WS_QW2T, pri_b2, ws + WS_QW3T, pri_b3, out);

  // fused decoder (declin..deconv3)
  k_dec<<<NF, 256, 0, stream>>>(HS, out + OUT_ZS, ws + WS_DECT, dec_pb,
                                WD1, dec_b1, WD2, dec_b2, dec_w3, dec_b3, out);
}